// Round 1
// baseline (1505.078 us; speedup 1.0000x reference)
//
#include <hip/hip_runtime.h>
#include <hip/hip_bf16.h>

// Problem constants
#define Bc 2
#define Sc 2048
#define Ec 512
#define Hc 8
#define Lc 4
#define Vc 10000
#define Dc 64
#define Mc (Bc*Sc)   // 4096

typedef __hip_bfloat16 bf16;
typedef __attribute__((ext_vector_type(8))) short frag_ab;   // 8 bf16 (4 VGPRs)
typedef __attribute__((ext_vector_type(4))) float frag_cd;   // 4 fp32 acc

static __device__ __forceinline__ frag_ab ldfrag(const bf16* p) {
  return *(const frag_ab*)p;
}

// ---------------- fp32 -> bf16 convert ----------------
__global__ void f2b_kernel(const float* __restrict__ in, bf16* __restrict__ out) {
  int i = blockIdx.x * 256 + threadIdx.x;
  out[i] = __float2bfloat16(in[i]);
}

// ---------------- embedding + positional --------------
__global__ void embed_kernel(const int* __restrict__ tok, const float* __restrict__ emb,
                             const float* __restrict__ pos, float* __restrict__ x,
                             bf16* __restrict__ xb) {
  int i = blockIdx.x * 256 + threadIdx.x;      // over Mc*Ec
  int row = i >> 9, c = i & 511;
  int s = row & (Sc - 1);
  float v = emb[tok[row] * Ec + c] + pos[s * Ec + c];
  x[i] = v;
  xb[i] = __float2bfloat16(v);
}

// ---------------- unified GEMM: C = A(bf16 MxK rm) @ W(bf16 NxK rm)^T + bias ----
// Wave computes a 16(m) x 64(n) tile; block = 4 waves -> 64x64.
// mode 0: out bf16 [B,H,S,D] (q/k layout)
// mode 2: out bf16 [B,H,D,S] (v transposed layout)
// mode 3: out fp32 row-major [M, Nvalid]
__global__ void gemm_bt(const bf16* __restrict__ A, const bf16* __restrict__ W,
                        const float* __restrict__ bias, void* __restrict__ out,
                        int Nvalid, int mode) {
  int lane = threadIdx.x & 63;
  int wv = threadIdx.x >> 6;
  int c = lane & 15, quad = lane >> 4;
  int m0 = blockIdx.x * 64 + wv * 16;
  int n0 = blockIdx.y * 64;
  frag_cd acc[4] = {};
  const bf16* ar = A + (m0 + c) * Ec + quad * 8;   // A fragment row = lane&15
  for (int k = 0; k < Ec; k += 32) {
    frag_ab a = ldfrag(ar + k);
#pragma unroll
    for (int t = 0; t < 4; ++t) {
      int n = n0 + t * 16;
      if (n < Nvalid) {
        frag_ab b = ldfrag(W + (n + c) * Ec + k + quad * 8);  // B[k][n] = W[n][k]
        acc[t] = __builtin_amdgcn_mfma_f32_16x16x32_bf16(a, b, acc[t], 0, 0, 0);
      }
    }
  }
  // C/D layout: col = lane&15, row = quad*4 + reg
#pragma unroll
  for (int t = 0; t < 4; ++t) {
    int nb = n0 + t * 16;
    if (nb >= Nvalid) continue;
    int gn = nb + c;
    float bv = bias[gn];
#pragma unroll
    for (int i = 0; i < 4; ++i) {
      int gm = m0 + quad * 4 + i;
      float v = acc[t][i] + bv;
      if (mode == 0) {
        int bb = gm >> 11, ss = gm & (Sc - 1), hh = gn >> 6, dd = gn & 63;
        ((bf16*)out)[(((bb << 3) + hh) * Sc + ss) * Dc + dd] = __float2bfloat16(v);
      } else if (mode == 2) {
        int bb = gm >> 11, ss = gm & (Sc - 1), hh = gn >> 6, dd = gn & 63;
        ((bf16*)out)[(((bb << 3) + hh) * Dc + dd) * Sc + ss] = __float2bfloat16(v);
      } else {
        ((float*)out)[(long)gm * Nvalid + gn] = v;
      }
    }
  }
}

// ---------------- fused flash attention ----------------
// One wave per 16 Q rows of one (b,h). K tiles of 32 keys.
// Q,K: bf16 [B,H,S,D]; Vt: bf16 [B,H,D,S]; O: bf16 [B,S,E] (heads concatenated)
__global__ void attn_kernel(const bf16* __restrict__ Q, const bf16* __restrict__ Kb,
                            const bf16* __restrict__ Vt, bf16* __restrict__ O) {
  __shared__ bf16 lds_p[4][16 * 32];
  int lane = threadIdx.x & 63, wv = threadIdx.x >> 6;
  int wid = blockIdx.x * 4 + wv;
  int bh = wid >> 7;                 // 0..15
  int q0 = (wid & 127) << 4;         // Q row tile base
  int c = lane & 15, quad = lane >> 4;

  const bf16* qp = Q + ((long)bh * Sc + q0 + c) * Dc + quad * 8;
  frag_ab aq0 = ldfrag(qp);
  frag_ab aq1 = ldfrag(qp + 32);

  float m_i[4], l_i[4];
  frag_cd o[4] = {};
#pragma unroll
  for (int i = 0; i < 4; ++i) { m_i[i] = -1e30f; l_i[i] = 0.f; }

  const bf16* kbase = Kb + (long)bh * Sc * Dc;
  const bf16* vbase = Vt + (long)bh * Dc * Sc;

  for (int k0 = 0; k0 < Sc; k0 += 32) {
    const bf16* kp = kbase + (k0 + c) * Dc + quad * 8;
    frag_ab b00 = ldfrag(kp);
    frag_ab b01 = ldfrag(kp + 32);
    frag_ab b10 = ldfrag(kp + 16 * Dc);
    frag_ab b11 = ldfrag(kp + 16 * Dc + 32);
    frag_cd s0 = {}, s1 = {};
    s0 = __builtin_amdgcn_mfma_f32_16x16x32_bf16(aq0, b00, s0, 0, 0, 0);
    s0 = __builtin_amdgcn_mfma_f32_16x16x32_bf16(aq1, b01, s0, 0, 0, 0);
    s1 = __builtin_amdgcn_mfma_f32_16x16x32_bf16(aq0, b10, s1, 0, 0, 0);
    s1 = __builtin_amdgcn_mfma_f32_16x16x32_bf16(aq1, b11, s1, 0, 0, 0);

    float p0[4], p1[4], alpha[4];
#pragma unroll
    for (int i = 0; i < 4; ++i) {
      float sa = s0[i] * 0.125f, sb = s1[i] * 0.125f;
      float mx = fmaxf(sa, sb);
#pragma unroll
      for (int d = 1; d < 16; d <<= 1) mx = fmaxf(mx, __shfl_xor(mx, d, 64));
      float mn = fmaxf(m_i[i], mx);
      alpha[i] = __expf(m_i[i] - mn);
      p0[i] = __expf(sa - mn);
      p1[i] = __expf(sb - mn);
      float rs = p0[i] + p1[i];
#pragma unroll
      for (int d = 1; d < 16; d <<= 1) rs += __shfl_xor(rs, d, 64);
      l_i[i] = l_i[i] * alpha[i] + rs;
      m_i[i] = mn;
    }
    // P: C-layout -> LDS [16 rows][32 keys] -> A-layout fragment
    bf16* pl = lds_p[wv];
#pragma unroll
    for (int i = 0; i < 4; ++i) {
      int r = quad * 4 + i;
      pl[r * 32 + c]      = __float2bfloat16(p0[i]);
      pl[r * 32 + 16 + c] = __float2bfloat16(p1[i]);
    }
    frag_ab ap = ldfrag(pl + c * 32 + quad * 8);
#pragma unroll
    for (int t = 0; t < 4; ++t) {
#pragma unroll
      for (int i = 0; i < 4; ++i) o[t][i] *= alpha[i];
      frag_ab bv = ldfrag(vbase + (t * 16 + c) * Sc + k0 + quad * 8);
      o[t] = __builtin_amdgcn_mfma_f32_16x16x32_bf16(ap, bv, o[t], 0, 0, 0);
    }
  }

  int bb = bh >> 3, hh = bh & 7;
#pragma unroll
  for (int i = 0; i < 4; ++i) {
    float inv = 1.f / l_i[i];
    int ss = q0 + quad * 4 + i;
#pragma unroll
    for (int t = 0; t < 4; ++t) {
      O[((long)bb * Sc + ss) * Ec + hh * Dc + t * 16 + c] =
          __float2bfloat16(o[t][i] * inv);
    }
  }
}

// ---------------- residual + layernorm ----------------
// x_new = LN(x + a) * g + b ; writes fp32 x and bf16 xb. One wave per row.
__global__ void ln_kernel(const float* __restrict__ x, const float* __restrict__ a,
                          const float* __restrict__ g, const float* __restrict__ bb,
                          float* __restrict__ xo, bf16* __restrict__ xbo) {
  int lane = threadIdx.x & 63, wv = threadIdx.x >> 6;
  int row = blockIdx.x * 4 + wv;
  const float* xr = x + (long)row * Ec;
  const float* ar = a + (long)row * Ec;
  float v[8];
  float sum = 0.f;
#pragma unroll
  for (int j = 0; j < 8; ++j) {
    int c = lane + j * 64;
    v[j] = xr[c] + ar[c];
    sum += v[j];
  }
#pragma unroll
  for (int d = 1; d < 64; d <<= 1) sum += __shfl_xor(sum, d, 64);
  float mu = sum * (1.f / 512.f);
  float sq = 0.f;
#pragma unroll
  for (int j = 0; j < 8; ++j) { float t = v[j] - mu; sq += t * t; }
#pragma unroll
  for (int d = 1; d < 64; d <<= 1) sq += __shfl_xor(sq, d, 64);
  float rs = 1.f / sqrtf(sq * (1.f / 512.f) + 1e-5f);
#pragma unroll
  for (int j = 0; j < 8; ++j) {
    int c = lane + j * 64;
    float y = (v[j] - mu) * rs * g[c] + bb[c];
    xo[(long)row * Ec + c] = y;
    xbo[(long)row * Ec + c] = __float2bfloat16(y);
  }
}

extern "C" void kernel_launch(void* const* d_in, const int* in_sizes, int n_in,
                              void* d_out, int out_size, void* d_ws, size_t ws_size,
                              hipStream_t stream) {
  // Input order per setup_inputs():
  const int*   tokens = (const int*)d_in[0];
  const float* embed  = (const float*)d_in[1];
  const float* pos    = (const float*)d_in[2];
  const float* Wq     = (const float*)d_in[3];
  const float* bq     = (const float*)d_in[4];
  const float* Wk     = (const float*)d_in[5];
  const float* bk     = (const float*)d_in[6];
  const float* Wv     = (const float*)d_in[7];
  const float* bv     = (const float*)d_in[8];
  const float* Wo     = (const float*)d_in[9];
  const float* bo     = (const float*)d_in[10];
  const float* ln_g   = (const float*)d_in[11];
  const float* ln_b   = (const float*)d_in[12];
  const float* Wout   = (const float*)d_in[13];
  const float* bout   = (const float*)d_in[14];
  float* out = (float*)d_out;

  // Workspace layout
  char* ws = (char*)d_ws;
  size_t off = 0;
  float* x_f   = (float*)(ws + off); off += (size_t)Mc * Ec * 4;     // 8 MB
  bf16*  xb    = (bf16*)(ws + off);  off += (size_t)Mc * Ec * 2;     // 4 MB
  float* a_f   = (float*)(ws + off); off += (size_t)Mc * Ec * 4;     // 8 MB
  bf16*  qb    = (bf16*)(ws + off);  off += (size_t)Mc * Ec * 2;
  bf16*  kb    = (bf16*)(ws + off);  off += (size_t)Mc * Ec * 2;
  bf16*  vtb   = (bf16*)(ws + off);  off += (size_t)Mc * Ec * 2;
  bf16*  attn  = (bf16*)(ws + off);  off += (size_t)Mc * Ec * 2;
  bf16*  wq_b  = (bf16*)(ws + off);  off += (size_t)Lc * Ec * Ec * 2;
  bf16*  wk_b  = (bf16*)(ws + off);  off += (size_t)Lc * Ec * Ec * 2;
  bf16*  wv_b  = (bf16*)(ws + off);  off += (size_t)Lc * Ec * Ec * 2;
  bf16*  wo_b  = (bf16*)(ws + off);  off += (size_t)Lc * Ec * Ec * 2;
  bf16*  wout_b = (bf16*)(ws + off); off += (size_t)Vc * Ec * 2;

  // 1) weight conversion
  int wn = Lc * Ec * Ec;                       // 1,048,576
  f2b_kernel<<<wn / 256, 256, 0, stream>>>(Wq, wq_b);
  f2b_kernel<<<wn / 256, 256, 0, stream>>>(Wk, wk_b);
  f2b_kernel<<<wn / 256, 256, 0, stream>>>(Wv, wv_b);
  f2b_kernel<<<wn / 256, 256, 0, stream>>>(Wo, wo_b);
  f2b_kernel<<<(Vc * Ec) / 256, 256, 0, stream>>>(Wout, wout_b);   // 5,120,000

  // 2) embedding
  embed_kernel<<<(Mc * Ec) / 256, 256, 0, stream>>>(tokens, embed, pos, x_f, xb);

  // 3) layers
  dim3 ggemm(Mc / 64, Ec / 64);   // (64, 8)
  for (int l = 0; l < Lc; ++l) {
    const bf16* wq_l = wq_b + (size_t)l * Ec * Ec;
    const bf16* wk_l = wk_b + (size_t)l * Ec * Ec;
    const bf16* wv_l = wv_b + (size_t)l * Ec * Ec;
    const bf16* wo_l = wo_b + (size_t)l * Ec * Ec;
    gemm_bt<<<ggemm, 256, 0, stream>>>(xb, wq_l, bq + l * Ec, qb, Ec, 0);
    gemm_bt<<<ggemm, 256, 0, stream>>>(xb, wk_l, bk + l * Ec, kb, Ec, 0);
    gemm_bt<<<ggemm, 256, 0, stream>>>(xb, wv_l, bv + l * Ec, vtb, Ec, 2);
    attn_kernel<<<(Bc * Hc * (Sc / 16)) / 4, 256, 0, stream>>>(qb, kb, vtb, attn);
    gemm_bt<<<ggemm, 256, 0, stream>>>(attn, wo_l, bo + l * Ec, a_f, Ec, 3);
    ln_kernel<<<Mc / 4, 256, 0, stream>>>(x_f, a_f, ln_g + l * Ec, ln_b + l * Ec,
                                          x_f, xb);
  }

  // 4) logits: [M, V] fp32
  dim3 glog(Mc / 64, (Vc + 63) / 64);   // (64, 157)
  gemm_bt<<<glog, 256, 0, stream>>>(xb, wout_b, bout, out, Vc, 3);
}

// Round 2
// 923.550 us; speedup vs baseline: 1.6297x; 1.6297x over previous
//
#include <hip/hip_runtime.h>
#include <hip/hip_bf16.h>

// Problem constants
#define Bc 2
#define Sc 2048
#define Ec 512
#define Hc 8
#define Lc 4
#define Vc 10000
#define Dc 64
#define Mc (Bc*Sc)   // 4096
#define NPAD 10112   // 79*128, padded vocab rows

typedef __hip_bfloat16 bf16;
typedef __attribute__((ext_vector_type(8))) short frag_ab;   // 8 bf16 (4 VGPRs)
typedef __attribute__((ext_vector_type(4))) float frag_cd;   // 4 fp32 acc

typedef __attribute__((address_space(3))) void lds_t;
typedef __attribute__((address_space(1))) void gm_t;
static __device__ __forceinline__ void gload16(const void* g, void* l) {
  __builtin_amdgcn_global_load_lds((const gm_t*)g, (lds_t*)l, 16, 0, 0);
}

// ---------------- fused weight convert (fp32 -> bf16) ----------------
// wqkv: [L][1536][512] (Wq/Wk/Wv rows concatenated per layer)
// wo:   [L][512][512]
// wout: [NPAD][512], rows >= Vc zeroed
#define NQKV (Lc*1536*512)      // 3,145,728
#define NO   (Lc*512*512)       // 1,048,576
#define NOUT (NPAD*512)         // 5,177,344
__global__ void convert_kernel(const float* __restrict__ Wq, const float* __restrict__ Wk,
                               const float* __restrict__ Wv, const float* __restrict__ Wo,
                               const float* __restrict__ Wout,
                               bf16* __restrict__ wqkv, bf16* __restrict__ wo,
                               bf16* __restrict__ wout) {
  long i4 = (long)(blockIdx.x * 256 + threadIdx.x) * 4;
  if (i4 >= NQKV + NO + NOUT) return;
  float4 v;
  bf16* dst;
  if (i4 < NQKV) {
    int row = (int)(i4 >> 9), colb = (int)(i4 & 511);
    int l = row / 1536, rr = row - l * 1536;
    int seg = rr >> 9, r = rr & 511;
    const float* src = (seg == 0 ? Wq : seg == 1 ? Wk : Wv) + (((long)(l * 512 + r)) << 9) + colb;
    v = *(const float4*)src;
    dst = wqkv + i4;
  } else if (i4 < NQKV + NO) {
    long j = i4 - NQKV;
    v = *(const float4*)(Wo + j);
    dst = wo + j;
  } else {
    long j = i4 - NQKV - NO;
    int row = (int)(j >> 9);
    if (row < Vc) v = *(const float4*)(Wout + j);
    else { v.x = 0.f; v.y = 0.f; v.z = 0.f; v.w = 0.f; }
    dst = wout + j;
  }
  union { bf16 h[4]; short4 s4; } u;
  u.h[0] = __float2bfloat16(v.x);
  u.h[1] = __float2bfloat16(v.y);
  u.h[2] = __float2bfloat16(v.z);
  u.h[3] = __float2bfloat16(v.w);
  *(short4*)dst = u.s4;
}

// ---------------- embedding + positional --------------
__global__ void embed_kernel(const int* __restrict__ tok, const float* __restrict__ emb,
                             const float* __restrict__ pos, float* __restrict__ x,
                             bf16* __restrict__ xb) {
  int i = blockIdx.x * 256 + threadIdx.x;      // over Mc*Ec
  int row = i >> 9, c = i & 511;
  int s = row & (Sc - 1);
  float v = emb[tok[row] * Ec + c] + pos[s * Ec + c];
  x[i] = v;
  xb[i] = __float2bfloat16(v);
}

// ---------------- tiled GEMM (m97 structure): C = A @ W^T + bias ----------------
// A: bf16 [M x 512] rm, W: bf16 [N x 512] rm. Block 256 thr = 4 waves, tile 128x128,
// BK=32, LDS staging via global_load_lds(16B) with XOR chunk swizzle in the global
// source address (LDS dest must be base + lane*16).
// MODE 0: QKV fused, N=1536. gn<512 -> q [B,H,S,D], <1024 -> k [B,H,S,D], else v [B,H,D,S]
// MODE 1: fp32 out [M,512] (O-proj, pre-residual)
// MODE 2: fp32 out [M,Vc], W padded to NPAD rows, store guarded gn<Vc
template<int MODE>
__global__ __launch_bounds__(256)
void gemm_tile(const bf16* __restrict__ A, const bf16* __restrict__ W,
               const float* __restrict__ b0, const float* __restrict__ b1,
               const float* __restrict__ b2,
               void* __restrict__ o0, void* __restrict__ o1, void* __restrict__ o2) {
  __shared__ bf16 As[128 * 32];
  __shared__ bf16 Bs[128 * 32];
  const int t = threadIdx.x;
  const int lane = t & 63;
  const int wv = t >> 6;
  const int c = lane & 15, quad = lane >> 4;
  const int m0 = blockIdx.x * 128, n0 = blockIdx.y * 128;
  const int wm = (wv & 1) * 64, wn = (wv >> 1) * 64;
  frag_cd acc[4][4] = {};

  // staging: physical 16B chunk p (0..511): r = p>>2, ch = p&3;
  // content = global chunk (r, g) with g = ch ^ ((r>>1)&3)  [XOR swizzle]
  const int p0 = t, p1 = t + 256;
  const int r0 = p0 >> 2, g0 = (p0 & 3) ^ ((r0 >> 1) & 3);
  const int r1 = p1 >> 2, g1 = (p1 & 3) ^ ((r1 >> 1) & 3);
  const bf16* a0 = A + (m0 + r0) * Ec + g0 * 8;
  const bf16* a1 = A + (m0 + r1) * Ec + g1 * 8;
  const bf16* w0 = W + (n0 + r0) * Ec + g0 * 8;
  const bf16* w1 = W + (n0 + r1) * Ec + g1 * 8;

  // compute-phase LDS read column chunk (self-inverse swizzle):
  const int sw8 = ((quad ^ ((c >> 1) & 3))) * 8;

  for (int k = 0; k < Ec; k += 32) {
    __syncthreads();
    gload16(a0 + k, As + p0 * 8);
    gload16(a1 + k, As + p1 * 8);
    gload16(w0 + k, Bs + p0 * 8);
    gload16(w1 + k, Bs + p1 * 8);
    __syncthreads();
    frag_ab af[4], bfr[4];
#pragma unroll
    for (int i = 0; i < 4; ++i)
      af[i] = *(const frag_ab*)(As + (wm + i * 16 + c) * 32 + sw8);
#pragma unroll
    for (int j = 0; j < 4; ++j)
      bfr[j] = *(const frag_ab*)(Bs + (wn + j * 16 + c) * 32 + sw8);
#pragma unroll
    for (int i = 0; i < 4; ++i)
#pragma unroll
      for (int j = 0; j < 4; ++j)
        acc[i][j] = __builtin_amdgcn_mfma_f32_16x16x32_bf16(af[i], bfr[j], acc[i][j], 0, 0, 0);
  }

  // Epilogue. C/D layout: col = lane&15 (=c), row = quad*4 + reg
#pragma unroll
  for (int j = 0; j < 4; ++j) {
    int gn = n0 + wn + j * 16 + c;
    if (MODE == 0) {
      int seg = gn >> 9, col = gn & 511;
      const float* bp = seg == 0 ? b0 : seg == 1 ? b1 : b2;
      float bias = bp[col];
      int hh = col >> 6, dd = col & 63;
#pragma unroll
      for (int i = 0; i < 4; ++i)
#pragma unroll
        for (int ii = 0; ii < 4; ++ii) {
          int gm = m0 + wm + i * 16 + quad * 4 + ii;
          int bb = gm >> 11, ss = gm & (Sc - 1);
          float v = acc[i][j][ii] + bias;
          if (seg == 0)
            ((bf16*)o0)[((((bb << 3) + hh) * Sc + ss) << 6) + dd] = __float2bfloat16(v);
          else if (seg == 1)
            ((bf16*)o1)[((((bb << 3) + hh) * Sc + ss) << 6) + dd] = __float2bfloat16(v);
          else
            ((bf16*)o2)[((((bb << 3) + hh) << 6) + dd) * Sc + ss] = __float2bfloat16(v);
        }
    } else if (MODE == 1) {
      float bias = b0[gn];
#pragma unroll
      for (int i = 0; i < 4; ++i)
#pragma unroll
        for (int ii = 0; ii < 4; ++ii) {
          int gm = m0 + wm + i * 16 + quad * 4 + ii;
          ((float*)o0)[((long)gm << 9) + gn] = acc[i][j][ii] + bias;
        }
    } else {
      if (gn < Vc) {
        float bias = b0[gn];
#pragma unroll
        for (int i = 0; i < 4; ++i)
#pragma unroll
          for (int ii = 0; ii < 4; ++ii) {
            int gm = m0 + wm + i * 16 + quad * 4 + ii;
            ((float*)o0)[(long)gm * Vc + gn] = acc[i][j][ii] + bias;
          }
      }
    }
  }
}

// ---------------- fused flash attention (unchanged from R1, known-correct) ----------------
__global__ void attn_kernel(const bf16* __restrict__ Q, const bf16* __restrict__ Kb,
                            const bf16* __restrict__ Vt, bf16* __restrict__ O) {
  __shared__ bf16 lds_p[4][16 * 32];
  int lane = threadIdx.x & 63, wv = threadIdx.x >> 6;
  int wid = blockIdx.x * 4 + wv;
  int bh = wid >> 7;                 // 0..15
  int q0 = (wid & 127) << 4;         // Q row tile base
  int c = lane & 15, quad = lane >> 4;

  const bf16* qp = Q + ((long)bh * Sc + q0 + c) * Dc + quad * 8;
  frag_ab aq0 = *(const frag_ab*)qp;
  frag_ab aq1 = *(const frag_ab*)(qp + 32);

  float m_i[4], l_i[4];
  frag_cd o[4] = {};
#pragma unroll
  for (int i = 0; i < 4; ++i) { m_i[i] = -1e30f; l_i[i] = 0.f; }

  const bf16* kbase = Kb + (long)bh * Sc * Dc;
  const bf16* vbase = Vt + (long)bh * Dc * Sc;

  for (int k0 = 0; k0 < Sc; k0 += 32) {
    const bf16* kp = kbase + (k0 + c) * Dc + quad * 8;
    frag_ab b00 = *(const frag_ab*)kp;
    frag_ab b01 = *(const frag_ab*)(kp + 32);
    frag_ab b10 = *(const frag_ab*)(kp + 16 * Dc);
    frag_ab b11 = *(const frag_ab*)(kp + 16 * Dc + 32);
    frag_cd s0 = {}, s1 = {};
    s0 = __builtin_amdgcn_mfma_f32_16x16x32_bf16(aq0, b00, s0, 0, 0, 0);
    s0 = __builtin_amdgcn_mfma_f32_16x16x32_bf16(aq1, b01, s0, 0, 0, 0);
    s1 = __builtin_amdgcn_mfma_f32_16x16x32_bf16(aq0, b10, s1, 0, 0, 0);
    s1 = __builtin_amdgcn_mfma_f32_16x16x32_bf16(aq1, b11, s1, 0, 0, 0);

    float p0[4], p1[4], alpha[4];
#pragma unroll
    for (int i = 0; i < 4; ++i) {
      float sa = s0[i] * 0.125f, sb = s1[i] * 0.125f;
      float mx = fmaxf(sa, sb);
#pragma unroll
      for (int d = 1; d < 16; d <<= 1) mx = fmaxf(mx, __shfl_xor(mx, d, 64));
      float mn = fmaxf(m_i[i], mx);
      alpha[i] = __expf(m_i[i] - mn);
      p0[i] = __expf(sa - mn);
      p1[i] = __expf(sb - mn);
      float rs = p0[i] + p1[i];
#pragma unroll
      for (int d = 1; d < 16; d <<= 1) rs += __shfl_xor(rs, d, 64);
      l_i[i] = l_i[i] * alpha[i] + rs;
      m_i[i] = mn;
    }
    bf16* pl = lds_p[wv];
#pragma unroll
    for (int i = 0; i < 4; ++i) {
      int r = quad * 4 + i;
      pl[r * 32 + c]      = __float2bfloat16(p0[i]);
      pl[r * 32 + 16 + c] = __float2bfloat16(p1[i]);
    }
    frag_ab ap = *(const frag_ab*)(pl + c * 32 + quad * 8);
#pragma unroll
    for (int t = 0; t < 4; ++t) {
#pragma unroll
      for (int i = 0; i < 4; ++i) o[t][i] *= alpha[i];
      frag_ab bv = *(const frag_ab*)(vbase + (t * 16 + c) * Sc + k0 + quad * 8);
      o[t] = __builtin_amdgcn_mfma_f32_16x16x32_bf16(ap, bv, o[t], 0, 0, 0);
    }
  }

  int bb = bh >> 3, hh = bh & 7;
#pragma unroll
  for (int i = 0; i < 4; ++i) {
    float inv = 1.f / l_i[i];
    int ss = q0 + quad * 4 + i;
#pragma unroll
    for (int t = 0; t < 4; ++t) {
      O[((long)bb * Sc + ss) * Ec + hh * Dc + t * 16 + c] =
          __float2bfloat16(o[t][i] * inv);
    }
  }
}

// ---------------- residual + layernorm ----------------
__global__ void ln_kernel(const float* __restrict__ x, const float* __restrict__ a,
                          const float* __restrict__ g, const float* __restrict__ bb,
                          float* __restrict__ xo, bf16* __restrict__ xbo) {
  int lane = threadIdx.x & 63, wv = threadIdx.x >> 6;
  int row = blockIdx.x * 4 + wv;
  const float* xr = x + (long)row * Ec;
  const float* ar = a + (long)row * Ec;
  float v[8];
  float sum = 0.f;
#pragma unroll
  for (int j = 0; j < 8; ++j) {
    int c = lane + j * 64;
    v[j] = xr[c] + ar[c];
    sum += v[j];
  }
#pragma unroll
  for (int d = 1; d < 64; d <<= 1) sum += __shfl_xor(sum, d, 64);
  float mu = sum * (1.f / 512.f);
  float sq = 0.f;
#pragma unroll
  for (int j = 0; j < 8; ++j) { float t = v[j] - mu; sq += t * t; }
#pragma unroll
  for (int d = 1; d < 64; d <<= 1) sq += __shfl_xor(sq, d, 64);
  float rs = 1.f / sqrtf(sq * (1.f / 512.f) + 1e-5f);
#pragma unroll
  for (int j = 0; j < 8; ++j) {
    int c = lane + j * 64;
    float y = (v[j] - mu) * rs * g[c] + bb[c];
    xo[(long)row * Ec + c] = y;
    xbo[(long)row * Ec + c] = __float2bfloat16(y);
  }
}

extern "C" void kernel_launch(void* const* d_in, const int* in_sizes, int n_in,
                              void* d_out, int out_size, void* d_ws, size_t ws_size,
                              hipStream_t stream) {
  const int*   tokens = (const int*)d_in[0];
  const float* embed  = (const float*)d_in[1];
  const float* pos    = (const float*)d_in[2];
  const float* Wq     = (const float*)d_in[3];
  const float* bq     = (const float*)d_in[4];
  const float* Wk     = (const float*)d_in[5];
  const float* bk     = (const float*)d_in[6];
  const float* Wv     = (const float*)d_in[7];
  const float* bv     = (const float*)d_in[8];
  const float* Wo     = (const float*)d_in[9];
  const float* bo     = (const float*)d_in[10];
  const float* ln_g   = (const float*)d_in[11];
  const float* ln_b   = (const float*)d_in[12];
  const float* Wout   = (const float*)d_in[13];
  const float* bout   = (const float*)d_in[14];
  float* out = (float*)d_out;

  // Workspace layout
  char* ws = (char*)d_ws;
  size_t off = 0;
  float* x_f    = (float*)(ws + off); off += (size_t)Mc * Ec * 4;      // 8 MB
  bf16*  xb     = (bf16*)(ws + off);  off += (size_t)Mc * Ec * 2;      // 4 MB
  float* a_f    = (float*)(ws + off); off += (size_t)Mc * Ec * 4;      // 8 MB
  bf16*  qb     = (bf16*)(ws + off);  off += (size_t)Mc * Ec * 2;
  bf16*  kb     = (bf16*)(ws + off);  off += (size_t)Mc * Ec * 2;
  bf16*  vtb    = (bf16*)(ws + off);  off += (size_t)Mc * Ec * 2;
  bf16*  attnb  = (bf16*)(ws + off);  off += (size_t)Mc * Ec * 2;
  bf16*  wqkv_b = (bf16*)(ws + off);  off += (size_t)NQKV * 2;         // 6.3 MB
  bf16*  wo_b   = (bf16*)(ws + off);  off += (size_t)NO * 2;           // 2 MB
  bf16*  wout_b = (bf16*)(ws + off);  off += (size_t)NOUT * 2;         // 10.4 MB

  // 1) fused weight conversion (float4-vectorized, one launch)
  int nconv = (NQKV + NO + NOUT) / 4;           // 2,342,912
  convert_kernel<<<(nconv + 255) / 256, 256, 0, stream>>>(Wq, Wk, Wv, Wo, Wout,
                                                          wqkv_b, wo_b, wout_b);

  // 2) embedding
  embed_kernel<<<(Mc * Ec) / 256, 256, 0, stream>>>(tokens, embed, pos, x_f, xb);

  // 3) layers
  dim3 gqkv(Mc / 128, 1536 / 128);   // (32, 12)
  dim3 go(Mc / 128, Ec / 128);       // (32, 4)
  for (int l = 0; l < Lc; ++l) {
    const bf16* wqkv_l = wqkv_b + (size_t)l * 1536 * Ec;
    const bf16* wo_l   = wo_b + (size_t)l * Ec * Ec;
    gemm_tile<0><<<gqkv, 256, 0, stream>>>(xb, wqkv_l, bq + l * Ec, bk + l * Ec,
                                           bv + l * Ec, qb, kb, vtb);
    attn_kernel<<<(Bc * Hc * (Sc / 16)) / 4, 256, 0, stream>>>(qb, kb, vtb, attnb);
    gemm_tile<1><<<go, 256, 0, stream>>>(attnb, wo_l, bo + l * Ec, nullptr, nullptr,
                                         a_f, nullptr, nullptr);
    ln_kernel<<<Mc / 4, 256, 0, stream>>>(x_f, a_f, ln_g + l * Ec, ln_b + l * Ec,
                                          x_f, xb);
  }

  // 4) logits: [M, Vc] fp32, W padded to NPAD rows
  dim3 glog(Mc / 128, NPAD / 128);   // (32, 79)
  gemm_tile<2><<<glog, 256, 0, stream>>>(xb, wout_b, bout, nullptr, nullptr,
                                         out, nullptr, nullptr);
}

// Round 3
// 742.755 us; speedup vs baseline: 2.0263x; 1.2434x over previous
//
#include <hip/hip_runtime.h>
#include <hip/hip_bf16.h>

// Problem constants
#define Bc 2
#define Sc 2048
#define Ec 512
#define Hc 8
#define Lc 4
#define Vc 10000
#define Dc 64
#define Mc (Bc*Sc)   // 4096
#define NPAD 10112   // 79*128, padded vocab rows

typedef __hip_bfloat16 bf16;
typedef __attribute__((ext_vector_type(8))) short frag_ab;   // 8 bf16 (4 VGPRs)
typedef __attribute__((ext_vector_type(4))) float frag_cd;   // 4 fp32 acc

typedef __attribute__((address_space(3))) void lds_t;
typedef __attribute__((address_space(1))) void gm_t;
static __device__ __forceinline__ void gload16(const void* g, void* l) {
  __builtin_amdgcn_global_load_lds((const gm_t*)g, (lds_t*)l, 16, 0, 0);
}
static __device__ __forceinline__ frag_ab ldfrag(const bf16* p) {
  return *(const frag_ab*)p;
}

// ---------------- fused weight convert (fp32 -> bf16) ----------------
#define NQKV (Lc*1536*512)      // 3,145,728
#define NO   (Lc*512*512)       // 1,048,576
#define NOUT (NPAD*512)         // 5,177,344
__global__ void convert_kernel(const float* __restrict__ Wq, const float* __restrict__ Wk,
                               const float* __restrict__ Wv, const float* __restrict__ Wo,
                               const float* __restrict__ Wout,
                               bf16* __restrict__ wqkv, bf16* __restrict__ wo,
                               bf16* __restrict__ wout) {
  long i4 = (long)(blockIdx.x * 256 + threadIdx.x) * 4;
  if (i4 >= NQKV + NO + NOUT) return;
  float4 v;
  bf16* dst;
  if (i4 < NQKV) {
    int row = (int)(i4 >> 9), colb = (int)(i4 & 511);
    int l = row / 1536, rr = row - l * 1536;
    int seg = rr >> 9, r = rr & 511;
    const float* src = (seg == 0 ? Wq : seg == 1 ? Wk : Wv) + (((long)(l * 512 + r)) << 9) + colb;
    v = *(const float4*)src;
    dst = wqkv + i4;
  } else if (i4 < NQKV + NO) {
    long j = i4 - NQKV;
    v = *(const float4*)(Wo + j);
    dst = wo + j;
  } else {
    long j = i4 - NQKV - NO;
    int row = (int)(j >> 9);
    if (row < Vc) v = *(const float4*)(Wout + j);
    else { v.x = 0.f; v.y = 0.f; v.z = 0.f; v.w = 0.f; }
    dst = wout + j;
  }
  union { bf16 h[4]; short4 s4; } u;
  u.h[0] = __float2bfloat16(v.x);
  u.h[1] = __float2bfloat16(v.y);
  u.h[2] = __float2bfloat16(v.z);
  u.h[3] = __float2bfloat16(v.w);
  *(short4*)dst = u.s4;
}

// ---------------- embedding + positional --------------
__global__ void embed_kernel(const int* __restrict__ tok, const float* __restrict__ emb,
                             const float* __restrict__ pos, float* __restrict__ x,
                             bf16* __restrict__ xb) {
  int i = blockIdx.x * 256 + threadIdx.x;      // over Mc*Ec
  int row = i >> 9, c = i & 511;
  int s = row & (Sc - 1);
  float v = emb[tok[row] * Ec + c] + pos[s * Ec + c];
  x[i] = v;
  xb[i] = __float2bfloat16(v);
}

// ---------------- tiled GEMM (m97 structure): C = A @ W^T + bias ----------------
// MODE 0: QKV fused, N=1536. gn<512 -> q [B,H,S,D], <1024 -> k [B,H,S,D], else v [B,H,D,S]
// MODE 1: fp32 out [M,512] (O-proj, pre-residual)
// MODE 2: fp32 out [M,Vc], W padded to NPAD rows, store guarded gn<Vc
template<int MODE>
__global__ __launch_bounds__(256)
void gemm_tile(const bf16* __restrict__ A, const bf16* __restrict__ W,
               const float* __restrict__ b0, const float* __restrict__ b1,
               const float* __restrict__ b2,
               void* __restrict__ o0, void* __restrict__ o1, void* __restrict__ o2) {
  __shared__ bf16 As[128 * 32];
  __shared__ bf16 Bs[128 * 32];
  const int t = threadIdx.x;
  const int lane = t & 63;
  const int wv = t >> 6;
  const int c = lane & 15, quad = lane >> 4;
  const int m0 = blockIdx.x * 128, n0 = blockIdx.y * 128;
  const int wm = (wv & 1) * 64, wn = (wv >> 1) * 64;
  frag_cd acc[4][4] = {};

  const int p0 = t, p1 = t + 256;
  const int r0 = p0 >> 2, g0 = (p0 & 3) ^ ((r0 >> 1) & 3);
  const int r1 = p1 >> 2, g1 = (p1 & 3) ^ ((r1 >> 1) & 3);
  const bf16* a0 = A + (m0 + r0) * Ec + g0 * 8;
  const bf16* a1 = A + (m0 + r1) * Ec + g1 * 8;
  const bf16* w0 = W + (n0 + r0) * Ec + g0 * 8;
  const bf16* w1 = W + (n0 + r1) * Ec + g1 * 8;

  const int sw8 = ((quad ^ ((c >> 1) & 3))) * 8;

  for (int k = 0; k < Ec; k += 32) {
    __syncthreads();
    gload16(a0 + k, As + p0 * 8);
    gload16(a1 + k, As + p1 * 8);
    gload16(w0 + k, Bs + p0 * 8);
    gload16(w1 + k, Bs + p1 * 8);
    __syncthreads();
    frag_ab af[4], bfr[4];
#pragma unroll
    for (int i = 0; i < 4; ++i)
      af[i] = *(const frag_ab*)(As + (wm + i * 16 + c) * 32 + sw8);
#pragma unroll
    for (int j = 0; j < 4; ++j)
      bfr[j] = *(const frag_ab*)(Bs + (wn + j * 16 + c) * 32 + sw8);
#pragma unroll
    for (int i = 0; i < 4; ++i)
#pragma unroll
      for (int j = 0; j < 4; ++j)
        acc[i][j] = __builtin_amdgcn_mfma_f32_16x16x32_bf16(af[i], bfr[j], acc[i][j], 0, 0, 0);
  }

#pragma unroll
  for (int j = 0; j < 4; ++j) {
    int gn = n0 + wn + j * 16 + c;
    if (MODE == 0) {
      int seg = gn >> 9, col = gn & 511;
      const float* bp = seg == 0 ? b0 : seg == 1 ? b1 : b2;
      float bias = bp[col];
      int hh = col >> 6, dd = col & 63;
#pragma unroll
      for (int i = 0; i < 4; ++i)
#pragma unroll
        for (int ii = 0; ii < 4; ++ii) {
          int gm = m0 + wm + i * 16 + quad * 4 + ii;
          int bb = gm >> 11, ss = gm & (Sc - 1);
          float v = acc[i][j][ii] + bias;
          if (seg == 0)
            ((bf16*)o0)[((((bb << 3) + hh) * Sc + ss) << 6) + dd] = __float2bfloat16(v);
          else if (seg == 1)
            ((bf16*)o1)[((((bb << 3) + hh) * Sc + ss) << 6) + dd] = __float2bfloat16(v);
          else
            ((bf16*)o2)[((((bb << 3) + hh) << 6) + dd) * Sc + ss] = __float2bfloat16(v);
        }
    } else if (MODE == 1) {
      float bias = b0[gn];
#pragma unroll
      for (int i = 0; i < 4; ++i)
#pragma unroll
        for (int ii = 0; ii < 4; ++ii) {
          int gm = m0 + wm + i * 16 + quad * 4 + ii;
          ((float*)o0)[((long)gm << 9) + gn] = acc[i][j][ii] + bias;
        }
    } else {
      if (gn < Vc) {
        float bias = b0[gn];
#pragma unroll
        for (int i = 0; i < 4; ++i)
#pragma unroll
          for (int ii = 0; ii < 4; ++ii) {
            int gm = m0 + wm + i * 16 + quad * 4 + ii;
            ((float*)o0)[(long)gm * Vc + gn] = acc[i][j][ii] + bias;
          }
      }
    }
  }
}

// ---------------- flash attention, block-cooperative LDS staging ----------------
// Block = 4 waves = 64 Q rows of one (b,h); wave = 16 Q rows. 64-key tiles.
// K tile staged as Ks[2][64 keys][32 dims], V tile as Vs[2][64 dims][32 keys],
// both with the GEMM's XOR chunk swizzle (conflict-free ds_read_b128).
// P round-trips through per-wave swizzled LDS tile Ps[wv][16 rows][64 keys].
__global__ __launch_bounds__(256)
void attn_kernel(const bf16* __restrict__ Q, const bf16* __restrict__ Kb,
                 const bf16* __restrict__ Vt, bf16* __restrict__ O) {
  __shared__ bf16 Ks[2 * 64 * 32];
  __shared__ bf16 Vs[2 * 64 * 32];
  __shared__ bf16 Ps[4][16 * 64];
  const int t = threadIdx.x;
  const int lane = t & 63, wv = t >> 6;
  const int c = lane & 15, quad = lane >> 4;
  const int bh = blockIdx.x >> 5;               // 0..15
  const int q0 = (blockIdx.x & 31) * 64 + wv * 16;

  const bf16* kbase = Kb + (long)bh * Sc * Dc;
  const bf16* vbase = Vt + (long)bh * Dc * Sc;

  // staging: thread t stages chunks p0=t (kk=0) and p1=t+256 (kk=1)
  // chunk p: kk=p>>8, row=(p>>2)&63, c4=p&3; source column chunk g4 = c4 ^ ((row>>1)&3)
  const int p0 = t, p1 = t + 256;
  const int row0 = (p0 >> 2) & 63, g40 = (p0 & 3) ^ ((row0 >> 1) & 3);
  const int row1 = (p1 >> 2) & 63, g41 = (p1 & 3) ^ ((row1 >> 1) & 3);
  const bf16* ksrc0 = kbase + row0 * Dc + 0 * 32 + g40 * 8;
  const bf16* ksrc1 = kbase + row1 * Dc + 1 * 32 + g41 * 8;
  const bf16* vsrc0 = vbase + row0 * Sc + 0 * 32 + g40 * 8;
  const bf16* vsrc1 = vbase + row1 * Sc + 1 * 32 + g41 * 8;

  // Q fragments (held in registers for the whole pass)
  const bf16* qp = Q + ((long)bh * Sc + q0 + c) * Dc + quad * 8;
  frag_ab aq0 = ldfrag(qp);
  frag_ab aq1 = ldfrag(qp + 32);

  const int sw8 = (quad ^ ((c >> 1) & 3)) * 8;   // self-inverse column-chunk swizzle

  float m_i[4], l_i[4];
  frag_cd o[4] = {};
#pragma unroll
  for (int i = 0; i < 4; ++i) { m_i[i] = -1e30f; l_i[i] = 0.f; }

  for (int k0 = 0; k0 < Sc; k0 += 64) {
    __syncthreads();
    gload16(ksrc0 + k0 * Dc, Ks + p0 * 8);
    gload16(ksrc1 + k0 * Dc, Ks + p1 * 8);
    gload16(vsrc0 + k0, Vs + p0 * 8);
    gload16(vsrc1 + k0, Vs + p1 * 8);
    __syncthreads();

    // S = Q K^T over 64 keys (4 n-frags x 2 k-chunks)
    frag_cd s[4] = {};
#pragma unroll
    for (int j = 0; j < 4; ++j) {
      frag_ab kb0 = ldfrag(Ks + (j * 16 + c) * 32 + sw8);
      frag_ab kb1 = ldfrag(Ks + 2048 + (j * 16 + c) * 32 + sw8);
      s[j] = __builtin_amdgcn_mfma_f32_16x16x32_bf16(aq0, kb0, s[j], 0, 0, 0);
      s[j] = __builtin_amdgcn_mfma_f32_16x16x32_bf16(aq1, kb1, s[j], 0, 0, 0);
    }

    // online softmax (rows = quad*4 + i)
    float alpha[4], p[4][4];
#pragma unroll
    for (int i = 0; i < 4; ++i) {
      float sc0 = s[0][i] * 0.125f, sc1 = s[1][i] * 0.125f;
      float sc2 = s[2][i] * 0.125f, sc3 = s[3][i] * 0.125f;
      float mx = fmaxf(fmaxf(sc0, sc1), fmaxf(sc2, sc3));
#pragma unroll
      for (int d = 1; d < 16; d <<= 1) mx = fmaxf(mx, __shfl_xor(mx, d, 64));
      float mn = fmaxf(m_i[i], mx);
      alpha[i] = __expf(m_i[i] - mn);
      p[0][i] = __expf(sc0 - mn);
      p[1][i] = __expf(sc1 - mn);
      p[2][i] = __expf(sc2 - mn);
      p[3][i] = __expf(sc3 - mn);
      float rs = p[0][i] + p[1][i] + p[2][i] + p[3][i];
#pragma unroll
      for (int d = 1; d < 16; d <<= 1) rs += __shfl_xor(rs, d, 64);
      l_i[i] = l_i[i] * alpha[i] + rs;
      m_i[i] = mn;
    }

    // P: C-layout -> swizzled LDS tile [16 rows][64 keys]
    // phys 16B chunk = (key>>3) ^ (row&7); element = key&7
    bf16* pl = Ps[wv];
#pragma unroll
    for (int j = 0; j < 4; ++j)
#pragma unroll
      for (int i = 0; i < 4; ++i) {
        int row = quad * 4 + i;
        int key = j * 16 + c;
        pl[row * 64 + (((key >> 3) ^ (row & 7)) << 3) + (key & 7)] =
            __float2bfloat16(p[j][i]);
      }

    // rescale O, then PV over the 64-key tile (2 k-chunks x 4 d-tiles)
#pragma unroll
    for (int td = 0; td < 4; ++td)
#pragma unroll
      for (int i = 0; i < 4; ++i) o[td][i] *= alpha[i];
#pragma unroll
    for (int kk = 0; kk < 2; ++kk) {
      frag_ab ap = ldfrag(pl + c * 64 + ((((kk << 2) + quad) ^ (c & 7)) << 3));
#pragma unroll
      for (int td = 0; td < 4; ++td) {
        frag_ab vb = ldfrag(Vs + kk * 2048 + (td * 16 + c) * 32 + sw8);
        o[td] = __builtin_amdgcn_mfma_f32_16x16x32_bf16(ap, vb, o[td], 0, 0, 0);
      }
    }
  }

  const int bb = bh >> 3, hh = bh & 7;
#pragma unroll
  for (int i = 0; i < 4; ++i) {
    float inv = 1.f / l_i[i];
    int ss = q0 + quad * 4 + i;
#pragma unroll
    for (int td = 0; td < 4; ++td) {
      O[((long)bb * Sc + ss) * Ec + hh * Dc + td * 16 + c] =
          __float2bfloat16(o[td][i] * inv);
    }
  }
}

// ---------------- residual + layernorm ----------------
__global__ void ln_kernel(const float* __restrict__ x, const float* __restrict__ a,
                          const float* __restrict__ g, const float* __restrict__ bb,
                          float* __restrict__ xo, bf16* __restrict__ xbo) {
  int lane = threadIdx.x & 63, wv = threadIdx.x >> 6;
  int row = blockIdx.x * 4 + wv;
  const float* xr = x + (long)row * Ec;
  const float* ar = a + (long)row * Ec;
  float v[8];
  float sum = 0.f;
#pragma unroll
  for (int j = 0; j < 8; ++j) {
    int c = lane + j * 64;
    v[j] = xr[c] + ar[c];
    sum += v[j];
  }
#pragma unroll
  for (int d = 1; d < 64; d <<= 1) sum += __shfl_xor(sum, d, 64);
  float mu = sum * (1.f / 512.f);
  float sq = 0.f;
#pragma unroll
  for (int j = 0; j < 8; ++j) { float t = v[j] - mu; sq += t * t; }
#pragma unroll
  for (int d = 1; d < 64; d <<= 1) sq += __shfl_xor(sq, d, 64);
  float rs = 1.f / sqrtf(sq * (1.f / 512.f) + 1e-5f);
#pragma unroll
  for (int j = 0; j < 8; ++j) {
    int c = lane + j * 64;
    float y = (v[j] - mu) * rs * g[c] + bb[c];
    xo[(long)row * Ec + c] = y;
    xbo[(long)row * Ec + c] = __float2bfloat16(y);
  }
}

extern "C" void kernel_launch(void* const* d_in, const int* in_sizes, int n_in,
                              void* d_out, int out_size, void* d_ws, size_t ws_size,
                              hipStream_t stream) {
  const int*   tokens = (const int*)d_in[0];
  const float* embed  = (const float*)d_in[1];
  const float* pos    = (const float*)d_in[2];
  const float* Wq     = (const float*)d_in[3];
  const float* bq     = (const float*)d_in[4];
  const float* Wk     = (const float*)d_in[5];
  const float* bk     = (const float*)d_in[6];
  const float* Wv     = (const float*)d_in[7];
  const float* bv     = (const float*)d_in[8];
  const float* Wo     = (const float*)d_in[9];
  const float* bo     = (const float*)d_in[10];
  const float* ln_g   = (const float*)d_in[11];
  const float* ln_b   = (const float*)d_in[12];
  const float* Wout   = (const float*)d_in[13];
  const float* bout   = (const float*)d_in[14];
  float* out = (float*)d_out;

  // Workspace layout
  char* ws = (char*)d_ws;
  size_t off = 0;
  float* x_f    = (float*)(ws + off); off += (size_t)Mc * Ec * 4;      // 8 MB
  bf16*  xb     = (bf16*)(ws + off);  off += (size_t)Mc * Ec * 2;      // 4 MB
  float* a_f    = (float*)(ws + off); off += (size_t)Mc * Ec * 4;      // 8 MB
  bf16*  qb     = (bf16*)(ws + off);  off += (size_t)Mc * Ec * 2;
  bf16*  kb     = (bf16*)(ws + off);  off += (size_t)Mc * Ec * 2;
  bf16*  vtb    = (bf16*)(ws + off);  off += (size_t)Mc * Ec * 2;
  bf16*  attnb  = (bf16*)(ws + off);  off += (size_t)Mc * Ec * 2;
  bf16*  wqkv_b = (bf16*)(ws + off);  off += (size_t)NQKV * 2;         // 6.3 MB
  bf16*  wo_b   = (bf16*)(ws + off);  off += (size_t)NO * 2;           // 2 MB
  bf16*  wout_b = (bf16*)(ws + off);  off += (size_t)NOUT * 2;         // 10.4 MB

  // 1) fused weight conversion
  int nconv = (NQKV + NO + NOUT) / 4;
  convert_kernel<<<(nconv + 255) / 256, 256, 0, stream>>>(Wq, Wk, Wv, Wo, Wout,
                                                          wqkv_b, wo_b, wout_b);

  // 2) embedding
  embed_kernel<<<(Mc * Ec) / 256, 256, 0, stream>>>(tokens, embed, pos, x_f, xb);

  // 3) layers
  dim3 gqkv(Mc / 128, 1536 / 128);   // (32, 12)
  dim3 go(Mc / 128, Ec / 128);       // (32, 4)
  for (int l = 0; l < Lc; ++l) {
    const bf16* wqkv_l = wqkv_b + (size_t)l * 1536 * Ec;
    const bf16* wo_l   = wo_b + (size_t)l * Ec * Ec;
    gemm_tile<0><<<gqkv, 256, 0, stream>>>(xb, wqkv_l, bq + l * Ec, bk + l * Ec,
                                           bv + l * Ec, qb, kb, vtb);
    attn_kernel<<<Hc * Bc * (Sc / 64), 256, 0, stream>>>(qb, kb, vtb, attnb);
    gemm_tile<1><<<go, 256, 0, stream>>>(attnb, wo_l, bo + l * Ec, nullptr, nullptr,
                                         a_f, nullptr, nullptr);
    ln_kernel<<<Mc / 4, 256, 0, stream>>>(x_f, a_f, ln_g + l * Ec, ln_b + l * Ec,
                                          x_f, xb);
  }

  // 4) logits: [M, Vc] fp32, W padded to NPAD rows
  dim3 glog(Mc / 128, NPAD / 128);   // (32, 79)
  gemm_tile<2><<<glog, 256, 0, stream>>>(xb, wout_b, bout, nullptr, nullptr,
                                         out, nullptr, nullptr);
}